// Round 5
// baseline (429.274 us; speedup 1.0000x reference)
//
#include <hip/hip_runtime.h>

// Problem constants
#define Mq   8192     // B*T
#define Hq   1024
#define Sq   1024
#define Tq   1024
#define Vq   5000
#define Vpad 5120     // V padded to multiple of 128 for GEMM2 tiling

typedef __bf16 bf16;
typedef bf16  bf16x8 __attribute__((ext_vector_type(8)));
typedef bf16  bf16x4 __attribute__((ext_vector_type(4)));
typedef float f32x4  __attribute__((ext_vector_type(4)));

typedef const __attribute__((address_space(1))) void* gas_t;
typedef __attribute__((address_space(3))) void*       sas_t;

__device__ __forceinline__ void async_copy16(const void* g, void* s) {
  __builtin_amdgcn_global_load_lds((gas_t)g, (sas_t)s, 16, 0, 0);
}

// ---------------------------------------------------------------------------
// Kernel 1: fused x fp32 -> bf16 cast + p_gen = sigmoid(x @ Wg + bg)
// ---------------------------------------------------------------------------
__global__ __launch_bounds__(256) void pgen_cvt(
    const float* __restrict__ x, const float* __restrict__ Wg,
    const float* __restrict__ bg, bf16* __restrict__ xb,
    float* __restrict__ pgen) {
  const int m = blockIdx.x;
  const int t = threadIdx.x;
  float4 v = ((const float4*)(x + (size_t)m * Hq))[t];
  float4 g = ((const float4*)Wg)[t];
  float dot = v.x * g.x + v.y * g.y + v.z * g.z + v.w * g.w;
  bf16x4 o;
  o[0] = (bf16)v.x; o[1] = (bf16)v.y; o[2] = (bf16)v.z; o[3] = (bf16)v.w;
  ((bf16x4*)(xb + (size_t)m * Hq))[t] = o;
  #pragma unroll
  for (int off = 32; off; off >>= 1) dot += __shfl_down(dot, off, 64);
  __shared__ float red[4];
  if ((t & 63) == 0) red[t >> 6] = dot;
  __syncthreads();
  if (t == 0) {
    float s = red[0] + red[1] + red[2] + red[3] + bg[0];
    pgen[m] = 1.0f / (1.0f + __expf(-s));
  }
}

// ---------------------------------------------------------------------------
// Kernel 2/3: transpose + cast  W[K][Nin] fp32 -> WT[Npad][K] bf16 (zero pad)
// ---------------------------------------------------------------------------
__global__ __launch_bounds__(256) void transpose_cvt(
    const float* __restrict__ W, bf16* __restrict__ WT,
    int K, int Nin, int Npad) {
  __shared__ float tile[32][33];
  const int nb = blockIdx.x * 32, kb = blockIdx.y * 32;
  const int tx = threadIdx.x, ty = threadIdx.y;
  #pragma unroll
  for (int i = 0; i < 32; i += 8) {
    int k = kb + ty + i, n = nb + tx;
    tile[ty + i][tx] = (n < Nin) ? W[(size_t)k * Nin + n] : 0.0f;
  }
  __syncthreads();
  #pragma unroll
  for (int i = 0; i < 32; i += 8) {
    int n = nb + ty + i, k = kb + tx;
    if (n < Npad) WT[(size_t)n * K + k] = (bf16)tile[tx][ty + i];
  }
}

// ---------------------------------------------------------------------------
// MFMA GEMM: C = A @ BT^T (+bias, epilogue per MODE)
// MODE 0: h = gelu_tanh(C+bias) -> bf16, stride N
// MODE 1: e = exp(C+bias)       -> bf16, stride Nstore (cols >= Nstore skipped)
// MODE 2: e = exp(C+bias)       -> fp32, stride Nstore (fallback, into d_out)
// 1D grid, XCD-locality swizzle: xcd=bid&7 owns n-stripe of Q tiles x all m.
// 128x128 tile, BK=32, 4 waves 2x2, each wave 4x4 of 16x16x32 bf16 MFMA
// ---------------------------------------------------------------------------
template <int MODE, int Q>
__global__ __launch_bounds__(256, 2) void gemm_mfma(
    const bf16* __restrict__ A, const bf16* __restrict__ BT,
    const float* __restrict__ bias, float* __restrict__ outF,
    bf16* __restrict__ outB, int M, int N, int K, int Nstore) {
  __shared__ bf16 As[128 * 32];
  __shared__ bf16 Bs[128 * 32];
  const int bid = blockIdx.x;
  const int xcd = bid & 7;
  const int rr  = bid >> 3;
  const int nb  = xcd * Q + rr % Q;   // n-tile: XCD-local stripe
  const int mb  = rr / Q;             // m-tile: streams within stripe
  const int tid  = threadIdx.x;
  const int w    = tid >> 6;
  const int l    = tid & 63;
  const int quad = l >> 4;
  const int t16  = l & 15;
  const int wm   = (w >> 1) * 64;
  const int wn   = (w & 1) * 64;
  const int m0   = mb * 128;
  const int n0   = nb * 128;
  const int srow = l >> 2;
  const int scol = (l & 3) * 8;

  f32x4 acc[4][4] = {};

  for (int k0 = 0; k0 < K; k0 += 32) {
    __syncthreads();
    #pragma unroll
    for (int r = 0; r < 2; ++r) {
      const int chunk = r * 4 + w;
      const int mrow  = chunk * 16 + srow;
      async_copy16(A  + (size_t)(m0 + mrow) * K + k0 + scol, As + chunk * 512);
      async_copy16(BT + (size_t)(n0 + mrow) * K + k0 + scol, Bs + chunk * 512);
    }
    __syncthreads();

    bf16x8 af[4], bfr[4];
    #pragma unroll
    for (int i = 0; i < 4; ++i)
      af[i] = *(const bf16x8*)(As + (wm + 16 * i + t16) * 32 + quad * 8);
    #pragma unroll
    for (int j = 0; j < 4; ++j)
      bfr[j] = *(const bf16x8*)(Bs + (wn + 16 * j + t16) * 32 + quad * 8);
    #pragma unroll
    for (int i = 0; i < 4; ++i)
      #pragma unroll
      for (int j = 0; j < 4; ++j)
        acc[i][j] = __builtin_amdgcn_mfma_f32_16x16x32_bf16(af[i], bfr[j], acc[i][j], 0, 0, 0);
  }

  // hoist bias: depends only on j (col ng)
  float bj[4];
  #pragma unroll
  for (int j = 0; j < 4; ++j) {
    const int ng = n0 + wn + 16 * j + t16;
    bj[j] = (MODE == 0 || ng < Nstore) ? bias[ng] : 0.0f;
  }

  // epilogue: D element (row m, col n): m = wm+16i+quad*4+r, n = wn+16j+t16
  #pragma unroll
  for (int i = 0; i < 4; ++i) {
    const int mg = m0 + wm + 16 * i + quad * 4;
    #pragma unroll
    for (int j = 0; j < 4; ++j) {
      const int ng = n0 + wn + 16 * j + t16;
      #pragma unroll
      for (int r = 0; r < 4; ++r) {
        float v = acc[i][j][r] + bj[j];
        if (MODE == 0) {
          // gelu (tanh approx), tanh via __expf: tanh(u) = 1 - 2/(e^{2u}+1)
          float u  = 0.7978845608028654f * (v + 0.044715f * v * v * v);
          float e2 = __expf(2.0f * u);
          float th = 1.0f - 2.0f / (e2 + 1.0f);
          outB[(size_t)(mg + r) * N + ng] = (bf16)(0.5f * v * (1.0f + th));
        } else if (MODE == 1) {
          if (ng < Nstore)
            outB[(size_t)(mg + r) * Nstore + ng] = (bf16)__expf(v);
        } else {
          if (ng < Nstore)
            outF[(size_t)(mg + r) * Nstore + ng] = __expf(v);
        }
      }
    }
  }
}

// ---------------------------------------------------------------------------
// Finalize (fast, bf16 e): out[m][v] = e[m][v]*pg/S + scatter[v]*(1-pg)
// e row held in registers (24 bf16/thread); LDS only for scatter buffer.
// ---------------------------------------------------------------------------
__global__ __launch_bounds__(256) void finalize_fast(
    float* __restrict__ out, const bf16* __restrict__ e,
    const float* __restrict__ pgen, const float* __restrict__ attn,
    const int* __restrict__ nodes) {
  const int m = blockIdx.x;
  const int b = m / Tq;
  const int t = threadIdx.x;
  __shared__ float buf[Vq];
  __shared__ float red[4];

  // zero scatter buffer
  float4* buf4 = (float4*)buf;
  const float4 z4 = {0.f, 0.f, 0.f, 0.f};
  for (int i = t; i < Vq / 4; i += 256) buf4[i] = z4;

  // load e row into registers + running sum (625 bf16x8 chunks)
  const bf16x8* e8 = (const bf16x8*)(e + (size_t)m * Vq);
  bf16x8 ev[3];
  float s = 0.0f;
  #pragma unroll
  for (int c = 0; c < 3; ++c) {
    const int i = t + c * 256;
    if (i < Vq / 8) {
      ev[c] = e8[i];
      #pragma unroll
      for (int k = 0; k < 8; ++k) s += (float)ev[c][k];
    }
  }
  #pragma unroll
  for (int off = 32; off; off >>= 1) s += __shfl_down(s, off, 64);
  if ((t & 63) == 0) red[t >> 6] = s;
  __syncthreads();   // also covers buf zeroing
  s = red[0] + red[1] + red[2] + red[3];

  const float pg    = pgen[m];
  const float scale = pg / s;
  const float coefw = 1.0f - pg;

  // scatter attn mass into LDS (ds_add_f32)
  const float* arow = attn + (size_t)m * Sq;
  const int*   nrow = nodes + (size_t)b * Sq;
  for (int sIdx = t; sIdx < Sq; sIdx += 256)
    atomicAdd(&buf[nrow[sIdx]], arow[sIdx]);
  __syncthreads();

  // combine + write (each thread owns 8 consecutive floats per chunk)
  float4* o4 = (float4*)(out + (size_t)m * Vq);
  #pragma unroll
  for (int c = 0; c < 3; ++c) {
    const int i = t + c * 256;
    if (i < Vq / 8) {
      float f[8];
      #pragma unroll
      for (int k = 0; k < 8; ++k)
        f[k] = (float)ev[c][k] * scale + buf[i * 8 + k] * coefw;
      float4 lo = {f[0], f[1], f[2], f[3]};
      float4 hi = {f[4], f[5], f[6], f[7]};
      o4[i * 2 + 0] = lo;
      o4[i * 2 + 1] = hi;
    }
  }
}

// ---------------------------------------------------------------------------
// Fallback finalize (fp32 e in d_out, in-place per-row)
// ---------------------------------------------------------------------------
__global__ __launch_bounds__(256) void finalize_f32(
    float* __restrict__ out, const float* __restrict__ e,
    const float* __restrict__ pgen, const float* __restrict__ attn,
    const int* __restrict__ nodes) {
  const int m = blockIdx.x;
  const int b = m / Tq;
  const int t = threadIdx.x;
  __shared__ float buf[Vq];
  __shared__ float red[4];
  float s = 0.0f;
  const float4* e4 = (const float4*)(e + (size_t)m * Vq);
  for (int i = t; i < Vq / 4; i += 256) {
    float4 v = e4[i];
    buf[i * 4 + 0] = v.x; buf[i * 4 + 1] = v.y;
    buf[i * 4 + 2] = v.z; buf[i * 4 + 3] = v.w;
    s += (v.x + v.y) + (v.z + v.w);
  }
  #pragma unroll
  for (int off = 32; off; off >>= 1) s += __shfl_down(s, off, 64);
  if ((t & 63) == 0) red[t >> 6] = s;
  __syncthreads();
  s = red[0] + red[1] + red[2] + red[3];
  const float pg    = pgen[m];
  const float scale = pg / s;
  const float coef  = (1.0f - pg) / scale;
  const float* arow = attn + (size_t)m * Sq;
  const int*   nrow = nodes + (size_t)b * Sq;
  for (int sIdx = t; sIdx < Sq; sIdx += 256)
    atomicAdd(&buf[nrow[sIdx]], arow[sIdx] * coef);
  __syncthreads();
  float4* o4 = (float4*)(out + (size_t)m * Vq);
  const float4* b4 = (const float4*)buf;
  for (int i = t; i < Vq / 4; i += 256) {
    float4 v = b4[i];
    v.x *= scale; v.y *= scale; v.z *= scale; v.w *= scale;
    o4[i] = v;
  }
}

// ---------------------------------------------------------------------------
extern "C" void kernel_launch(void* const* d_in, const int* in_sizes, int n_in,
                              void* d_out, int out_size, void* d_ws, size_t ws_size,
                              hipStream_t stream) {
  const float* x    = (const float*)d_in[0];
  const float* attn = (const float*)d_in[1];
  const int*   nodes= (const int*)d_in[2];
  const float* Wg   = (const float*)d_in[3];
  const float* bg   = (const float*)d_in[4];
  const float* Wf   = (const float*)d_in[5];
  const float* bf_  = (const float*)d_in[6];
  const float* Wv   = (const float*)d_in[7];
  const float* bv   = (const float*)d_in[8];
  float* out = (float*)d_out;

  char* w = (char*)d_ws;
  const size_t NEED = 111312896ull;
  const bool big = ws_size >= NEED;

  if (big) {
    bf16*  eB   = (bf16*)(w);                      // overlaps xb (xb dead after gemm1)
    bf16*  xb   = (bf16*)(w);
    bf16*  hB   = (bf16*)(w + 81920000ull);
    bf16*  WfT  = (bf16*)(w + 98697216ull);
    bf16*  WvT  = (bf16*)(w + 100794368ull);
    float* pgen = (float*)(w + 111280128ull);

    pgen_cvt<<<Mq, 256, 0, stream>>>(x, Wg, bg, xb, pgen);
    transpose_cvt<<<dim3(Hq / 32, Hq / 32), dim3(32, 8), 0, stream>>>(Wf, WfT, Hq, Hq, Hq);
    transpose_cvt<<<dim3(Vpad / 32, Hq / 32), dim3(32, 8), 0, stream>>>(Wv, WvT, Hq, Vq, Vpad);
    gemm_mfma<0, 1><<<512, 256, 0, stream>>>(
        xb, WfT, bf_, nullptr, hB, Mq, Hq, Hq, Hq);
    gemm_mfma<1, 5><<<2560, 256, 0, stream>>>(
        hB, WvT, bv, nullptr, eB, Mq, Vpad, Hq, Vq);
    finalize_fast<<<Mq, 256, 0, stream>>>(out, eB, pgen, attn, nodes);
  } else {
    bf16*  xb   = (bf16*)(w);
    bf16*  hB   = (bf16*)(w + 16777216);
    bf16*  WfT  = (bf16*)(w + 33554432);
    bf16*  WvT  = (bf16*)(w + 35651584);
    float* pgen = (float*)(w + 46137344);

    pgen_cvt<<<Mq, 256, 0, stream>>>(x, Wg, bg, xb, pgen);
    transpose_cvt<<<dim3(Hq / 32, Hq / 32), dim3(32, 8), 0, stream>>>(Wf, WfT, Hq, Hq, Hq);
    transpose_cvt<<<dim3(Vpad / 32, Hq / 32), dim3(32, 8), 0, stream>>>(Wv, WvT, Hq, Vq, Vpad);
    gemm_mfma<0, 1><<<512, 256, 0, stream>>>(
        xb, WfT, bf_, nullptr, hB, Mq, Hq, Hq, Hq);
    gemm_mfma<2, 5><<<2560, 256, 0, stream>>>(
        hB, WvT, bv, out, nullptr, Mq, Vpad, Hq, Vq);
    finalize_f32<<<Mq, 256, 0, stream>>>(out, out, pgen, attn, nodes);
  }
}